// Round 2
// baseline (2883.493 us; speedup 1.0000x reference)
//
#include <hip/hip_runtime.h>

constexpr int FIN = 128;   // input feature dim
constexpr int FH  = 32;    // hidden dim

// ---- deg[d] += 1 per edge (self-loop added later as +1) ----
__global__ void k_deg(const int* __restrict__ dst, float* __restrict__ deg, int E) {
    int stride = gridDim.x * blockDim.x;
    for (int i = blockIdx.x * blockDim.x + threadIdx.x; i < E; i += stride)
        atomicAdd(&deg[dst[i]], 1.0f);
}

// ---- deg -> dinv in place: dinv = 1/sqrt(deg + 1) ----
__global__ void k_dinv(float* __restrict__ deg, int N) {
    int stride = gridDim.x * blockDim.x;
    for (int i = blockIdx.x * blockDim.x + threadIdx.x; i < N; i += stride)
        deg[i] = 1.0f / sqrtf(deg[i] + 1.0f);
}

// ---- h1 = x @ W1  ([N,128] @ [128,32]) ----
__global__ void k_gemm1(const float* __restrict__ x, const float* __restrict__ W1,
                        float* __restrict__ h1, int N) {
    __shared__ float Wl[FIN * FH];
    for (int t = threadIdx.x; t < FIN * FH; t += blockDim.x) Wl[t] = W1[t];
    __syncthreads();
    int stride = gridDim.x * blockDim.x;
    for (int row = blockIdx.x * blockDim.x + threadIdx.x; row < N; row += stride) {
        const float4* xr = (const float4*)(x + (size_t)row * FIN);
        float acc[FH];
#pragma unroll
        for (int f = 0; f < FH; f++) acc[f] = 0.0f;
        for (int k4 = 0; k4 < FIN / 4; k4++) {
            float4 xv = xr[k4];
            const float* w = &Wl[(k4 * 4) * FH];
#pragma unroll
            for (int f = 0; f < FH; f++)
                acc[f] += xv.x * w[f] + xv.y * w[FH + f] + xv.z * w[2 * FH + f] + xv.w * w[3 * FH + f];
        }
        float4* hr = (float4*)(h1 + (size_t)row * FH);
#pragma unroll
        for (int q = 0; q < FH / 4; q++)
            hr[q] = make_float4(acc[4 * q], acc[4 * q + 1], acc[4 * q + 2], acc[4 * q + 3]);
    }
}

// ---- per-edge scatter: acc1[d] += norm * h1[s]; csum[s] += dinv[d] ----
__global__ void k_scatter(const int* __restrict__ src, const int* __restrict__ dst,
                          const float* __restrict__ dinv, const float* __restrict__ h1,
                          float* __restrict__ acc1, float* __restrict__ csum, int E) {
    int stride = gridDim.x * blockDim.x;
    for (int i = blockIdx.x * blockDim.x + threadIdx.x; i < E; i += stride) {
        int s = src[i];
        int d = dst[i];
        float ds = dinv[s], dd = dinv[d];
        float nrm = ds * dd;
        atomicAdd(&csum[s], dd);
        const float4* hs = (const float4*)(h1 + (size_t)s * FH);
        float* od = acc1 + (size_t)d * FH;
#pragma unroll
        for (int q = 0; q < FH / 4; q++) {
            float4 v = hs[q];
            atomicAdd(&od[4 * q + 0], v.x * nrm);
            atomicAdd(&od[4 * q + 1], v.y * nrm);
            atomicAdd(&od[4 * q + 2], v.z * nrm);
            atomicAdd(&od[4 * q + 3], v.w * nrm);
        }
    }
}

// ---- epilogue: z = relu(acc1 + dinv^2*h1 + b1); y = z.W2; accum += c*y ----
__global__ void k_final(const float* __restrict__ acc1, const float* __restrict__ h1,
                        const float* __restrict__ dinv, const float* __restrict__ csum,
                        const float* __restrict__ b1, const float* __restrict__ W2,
                        float* __restrict__ accum, int N) {
    float b1r[FH], w2r[FH];
#pragma unroll
    for (int f = 0; f < FH; f++) { b1r[f] = b1[f]; w2r[f] = W2[f]; }
    float part = 0.0f;
    int stride = gridDim.x * blockDim.x;
    for (int i = blockIdx.x * blockDim.x + threadIdx.x; i < N; i += stride) {
        float di = dinv[i];
        float c  = di * (di + csum[i]);
        float di2 = di * di;
        const float4* ar = (const float4*)(acc1 + (size_t)i * FH);
        const float4* hr = (const float4*)(h1 + (size_t)i * FH);
        float y = 0.0f;
#pragma unroll
        for (int q = 0; q < FH / 4; q++) {
            float4 a = ar[q];
            float4 h = hr[q];
            float z0 = fmaxf(a.x + di2 * h.x + b1r[4 * q + 0], 0.0f);
            float z1 = fmaxf(a.y + di2 * h.y + b1r[4 * q + 1], 0.0f);
            float z2 = fmaxf(a.z + di2 * h.z + b1r[4 * q + 2], 0.0f);
            float z3 = fmaxf(a.w + di2 * h.w + b1r[4 * q + 3], 0.0f);
            y += z0 * w2r[4 * q + 0] + z1 * w2r[4 * q + 1] + z2 * w2r[4 * q + 2] + z3 * w2r[4 * q + 3];
        }
        part += c * y;
    }
#pragma unroll
    for (int off = 32; off > 0; off >>= 1) part += __shfl_down(part, off);
    if ((threadIdx.x & 63) == 0) atomicAdd(accum, part);
}

__global__ void k_out(const float* __restrict__ accum, const float* __restrict__ b2,
                      float* __restrict__ out, int N) {
    out[0] = accum[0] * (1.0f / (float)N) + b2[0];
}

extern "C" void kernel_launch(void* const* d_in, const int* in_sizes, int n_in,
                              void* d_out, int out_size, void* d_ws, size_t ws_size,
                              hipStream_t stream) {
    const float* x   = (const float*)d_in[0];
    const int*   ei  = (const int*)d_in[1];    // int64 in reference -> delivered as int32
    const float* W1  = (const float*)d_in[2];
    const float* b1  = (const float*)d_in[3];
    const float* W2  = (const float*)d_in[4];
    const float* b2  = (const float*)d_in[5];
    float*       out = (float*)d_out;

    int N = in_sizes[0] / FIN;   // 100000
    int E = in_sizes[1] / 2;     // 1600000
    const int* src = ei;
    const int* dst = ei + E;

    // workspace layout (floats):
    // [acc1: N*32][deg/dinv: N][csum: N][accum: 1 + pad 3][h1: N*32]
    float* w     = (float*)d_ws;
    float* acc1  = w;
    float* deg   = w + (size_t)N * FH;
    float* csum  = deg + N;
    float* accum = csum + N;
    float* h1    = accum + 4;   // keeps h1 16B-aligned

    size_t zero_bytes = ((size_t)N * FH + 2 * (size_t)N + 4) * sizeof(float);
    hipMemsetAsync(d_ws, 0, zero_bytes, stream);

    int thr = 256;
    int blkE = (E + thr - 1) / thr;
    int blkN = (N + thr - 1) / thr;

    k_deg<<<dim3(2048), dim3(thr), 0, stream>>>(dst, deg, E);
    k_dinv<<<dim3(blkN), dim3(thr), 0, stream>>>(deg, N);
    k_gemm1<<<dim3(blkN), dim3(thr), 0, stream>>>(x, W1, h1, N);
    k_scatter<<<dim3(blkE), dim3(thr), 0, stream>>>(src, dst, deg /*=dinv*/, h1, acc1, csum, E);
    k_final<<<dim3(blkN), dim3(thr), 0, stream>>>(acc1, h1, deg /*=dinv*/, csum, b1, W2, accum, N);
    k_out<<<dim3(1), dim3(1), 0, stream>>>(accum, b2, out, N);
}

// Round 3
// 485.503 us; speedup vs baseline: 5.9392x; 5.9392x over previous
//
#include <hip/hip_runtime.h>

constexpr int FIN = 128;   // input feature dim
constexpr int FH  = 32;    // hidden dim

// ---- degi[d] += 1 per edge (int histogram; self-loop added later as +1) ----
__global__ void k_deg(const int* __restrict__ dst, int* __restrict__ degi, int E) {
    int stride = gridDim.x * blockDim.x;
    for (int i = blockIdx.x * blockDim.x + threadIdx.x; i < E; i += stride)
        atomicAdd(&degi[dst[i]], 1);
}

// ---- dinv = 1/sqrt(deg + 1) ----
__global__ void k_dinv(const int* __restrict__ degi, float* __restrict__ dinv, int N) {
    int i = blockIdx.x * blockDim.x + threadIdx.x;
    if (i < N) dinv[i] = rsqrtf((float)degi[i] + 1.0f);
}

// ---- h1 = x @ W1  ([N,128] @ [128,32]) ----
__global__ void k_gemm1(const float* __restrict__ x, const float* __restrict__ W1,
                        float* __restrict__ h1, int N) {
    __shared__ float Wl[FIN * FH];
    for (int t = threadIdx.x; t < FIN * FH; t += blockDim.x) Wl[t] = W1[t];
    __syncthreads();
    int stride = gridDim.x * blockDim.x;
    for (int row = blockIdx.x * blockDim.x + threadIdx.x; row < N; row += stride) {
        const float4* xr = (const float4*)(x + (size_t)row * FIN);
        float acc[FH];
#pragma unroll
        for (int f = 0; f < FH; f++) acc[f] = 0.0f;
        for (int k4 = 0; k4 < FIN / 4; k4++) {
            float4 xv = xr[k4];
            const float* w = &Wl[(k4 * 4) * FH];
#pragma unroll
            for (int f = 0; f < FH; f++)
                acc[f] += xv.x * w[f] + xv.y * w[FH + f] + xv.z * w[2 * FH + f] + xv.w * w[3 * FH + f];
        }
        float4* hr = (float4*)(h1 + (size_t)row * FH);
#pragma unroll
        for (int q = 0; q < FH / 4; q++)
            hr[q] = make_float4(acc[4 * q], acc[4 * q + 1], acc[4 * q + 2], acc[4 * q + 3]);
    }
}

// ---- scan step 1: per-block (1024 elems) sums of degi ----
__global__ void k_scan_part(const int* __restrict__ degi, int* __restrict__ bsum, int N) {
    __shared__ int red[256];
    int t = threadIdx.x;
    int base = blockIdx.x * 1024 + t * 4;
    int s = 0;
#pragma unroll
    for (int j = 0; j < 4; j++) { int i = base + j; if (i < N) s += degi[i]; }
    red[t] = s;
    __syncthreads();
    for (int off = 128; off > 0; off >>= 1) {
        if (t < off) red[t] += red[t + off];
        __syncthreads();
    }
    if (t == 0) bsum[blockIdx.x] = red[0];
}

// ---- scan step 2: exclusive scan of block sums (single block, B<=1024) ----
__global__ void k_scan_bsum(int* __restrict__ bsum, int B) {
    __shared__ int lds[1024];
    int t = threadIdx.x;
    int orig = (t < B) ? bsum[t] : 0;
    lds[t] = orig;
    __syncthreads();
    for (int off = 1; off < 1024; off <<= 1) {
        int v = (t >= off) ? lds[t - off] : 0;
        __syncthreads();
        lds[t] += v;
        __syncthreads();
    }
    if (t < B) bsum[t] = lds[t] - orig;   // exclusive
}

// ---- scan step 3: write exclusive offsets ptr[] and working cursor cur[] ----
__global__ void k_scan_write(const int* __restrict__ degi, const int* __restrict__ bsum,
                             int* __restrict__ ptr, int* __restrict__ cur, int N) {
    __shared__ int red[256];
    int t = threadIdx.x;
    int base = blockIdx.x * 1024 + t * 4;
    int loc[4];
    int s = 0;
#pragma unroll
    for (int j = 0; j < 4; j++) {
        loc[j] = s;
        int i = base + j;
        if (i < N) s += degi[i];
    }
    red[t] = s;
    __syncthreads();
    for (int off = 1; off < 256; off <<= 1) {
        int v = (t >= off) ? red[t - off] : 0;
        __syncthreads();
        red[t] += v;
        __syncthreads();
    }
    int texcl = red[t] - s;
    int boff = bsum[blockIdx.x];
#pragma unroll
    for (int j = 0; j < 4; j++) {
        int i = base + j;
        if (i < N) {
            int p = boff + texcl + loc[j];
            ptr[i] = p;
            cur[i] = p;
        }
    }
}

// ---- CSR fill: eidx[cur[d]++] = s; csum[s] += dinv[d] ----
__global__ void k_fill(const int* __restrict__ src, const int* __restrict__ dst,
                       const float* __restrict__ dinv, int* __restrict__ cur,
                       int* __restrict__ eidx, float* __restrict__ csum, int E) {
    int stride = gridDim.x * blockDim.x;
    for (int i = blockIdx.x * blockDim.x + threadIdx.x; i < E; i += stride) {
        int s = src[i];
        int d = dst[i];
        int pos = atomicAdd(&cur[d], 1);
        eidx[pos] = s;
        atomicAdd(&csum[s], dinv[d]);
    }
}

// ---- gather + fused epilogue: 8 lanes per node, float4 features each ----
// acc = sum_{e in CSR[v]} dinv[s]*dinv[v]*h1[s] ; + self loop dinv^2*h1[v]
// z = relu(acc + b1); y = z.W2; contrib = dinv_v*(dinv_v + csum[v]) * y
__global__ void k_gather(const int* __restrict__ ptr, const int* __restrict__ degi,
                         const int* __restrict__ eidx, const float* __restrict__ dinv,
                         const float* __restrict__ csum, const float* __restrict__ h1,
                         const float* __restrict__ b1, const float* __restrict__ W2,
                         float* __restrict__ accum, int N) {
    int t = threadIdx.x;
    int g = (blockIdx.x * blockDim.x + t) >> 3;   // node id
    int l8 = t & 7;                               // lane within node group
    float contrib = 0.0f;
    if (g < N) {
        float dv = dinv[g];
        float4 acc = make_float4(0.f, 0.f, 0.f, 0.f);
        int beg = ptr[g];
        int end = beg + degi[g];
        for (int e = beg; e < end; e++) {
            int s = eidx[e];
            float nrm = dinv[s] * dv;
            float4 hv = *(const float4*)(h1 + (size_t)s * FH + l8 * 4);
            acc.x += nrm * hv.x;
            acc.y += nrm * hv.y;
            acc.z += nrm * hv.z;
            acc.w += nrm * hv.w;
        }
        // self-loop
        float dv2 = dv * dv;
        float4 hv = *(const float4*)(h1 + (size_t)g * FH + l8 * 4);
        float4 b4 = *(const float4*)(b1 + l8 * 4);
        float4 w4 = *(const float4*)(W2 + l8 * 4);
        float z0 = fmaxf(acc.x + dv2 * hv.x + b4.x, 0.0f);
        float z1 = fmaxf(acc.y + dv2 * hv.y + b4.y, 0.0f);
        float z2 = fmaxf(acc.z + dv2 * hv.z + b4.z, 0.0f);
        float z3 = fmaxf(acc.w + dv2 * hv.w + b4.w, 0.0f);
        float y = z0 * w4.x + z1 * w4.y + z2 * w4.z + z3 * w4.w;
        y += __shfl_xor(y, 1);
        y += __shfl_xor(y, 2);
        y += __shfl_xor(y, 4);
        if (l8 == 0) contrib = dv * (dv + csum[g]) * y;
    }
#pragma unroll
    for (int off = 32; off > 0; off >>= 1) contrib += __shfl_down(contrib, off);
    if ((t & 63) == 0) atomicAdd(accum, contrib);
}

__global__ void k_out(const float* __restrict__ accum, const float* __restrict__ b2,
                      float* __restrict__ out, int N) {
    out[0] = accum[0] * (1.0f / (float)N) + b2[0];
}

extern "C" void kernel_launch(void* const* d_in, const int* in_sizes, int n_in,
                              void* d_out, int out_size, void* d_ws, size_t ws_size,
                              hipStream_t stream) {
    const float* x   = (const float*)d_in[0];
    const int*   ei  = (const int*)d_in[1];    // int64 in reference -> delivered as int32
    const float* W1  = (const float*)d_in[2];
    const float* b1  = (const float*)d_in[3];
    const float* W2  = (const float*)d_in[4];
    const float* b2  = (const float*)d_in[5];
    float*       out = (float*)d_out;

    int N = in_sizes[0] / FIN;   // 100000
    int E = in_sizes[1] / 2;     // 1600000
    const int* src = ei;
    const int* dst = ei + E;

    // workspace layout (4-byte units):
    // [degi N][csum N][accum 4][dinv N][ptr N][cur N][bsum 1024][eidx E][h1 N*32]
    char* w = (char*)d_ws;
    int*   degi  = (int*)w;                         w += (size_t)N * 4;
    float* csum  = (float*)w;                       w += (size_t)N * 4;
    float* accum = (float*)w;                       w += 16;
    float* dinv  = (float*)w;                       w += (size_t)N * 4;
    int*   ptr   = (int*)w;                         w += (size_t)N * 4;
    int*   cur   = (int*)w;                         w += (size_t)N * 4;
    int*   bsum  = (int*)w;                         w += 1024 * 4;
    int*   eidx  = (int*)w;                         w += (size_t)E * 4;
    float* h1    = (float*)w;

    // zero degi, csum, accum (contiguous at front)
    hipMemsetAsync(d_ws, 0, (size_t)(2 * N + 4) * 4, stream);

    int thr = 256;
    int blkN = (N + thr - 1) / thr;
    int B    = (N + 1023) / 1024;     // scan blocks (98 for N=100000; must be <=1024)

    k_deg<<<dim3(2048), dim3(thr), 0, stream>>>(dst, degi, E);
    k_dinv<<<dim3(blkN), dim3(thr), 0, stream>>>(degi, dinv, N);
    k_gemm1<<<dim3(blkN), dim3(thr), 0, stream>>>(x, W1, h1, N);
    k_scan_part<<<dim3(B), dim3(thr), 0, stream>>>(degi, bsum, N);
    k_scan_bsum<<<dim3(1), dim3(1024), 0, stream>>>(bsum, B);
    k_scan_write<<<dim3(B), dim3(thr), 0, stream>>>(degi, bsum, ptr, cur, N);
    k_fill<<<dim3(4096), dim3(thr), 0, stream>>>(src, dst, dinv, cur, eidx, csum, E);
    int blkG = (N * 8 + thr - 1) / thr;
    k_gather<<<dim3(blkG), dim3(thr), 0, stream>>>(ptr, degi, eidx, dinv, csum, h1, b1, W2, accum, N);
    k_out<<<dim3(1), dim3(1), 0, stream>>>(accum, b2, out, N);
}